// Round 1
// baseline (231.961 us; speedup 1.0000x reference)
//
#include <hip/hip_runtime.h>

// SupProtoConLoss on MI355X.
// Strategy:
//  - cos Gram via bf16 MFMA 16x16x32 on normalized reps (bf16 error ~2.5e-4 in cos,
//    ~1e-3 in loss; threshold is 0.18 on a ~9.0 scalar).
//  - global max replaced by static shift S=10 (score <= (1+1e-8)/0.1); loss is
//    shift-invariant up to EPS terms (~1e-9 perturbation).
//  - symmetric: only upper-triangle 128x128 blocks computed; each tile scatters
//    row-sums AND col-sums (halves MFMA work).
//  - fused epilogue: pos-sum (same-label offdiag scores) + neg-sum (exp of
//    diff-label scores) per row via shfl reductions + fp32 global atomics.

#define NROW 8192
#define DDIM 512
#define NCLS 100

typedef float f32x4 __attribute__((ext_vector_type(4)));
typedef short s16x8 __attribute__((ext_vector_type(8)));

#define GLOBAL_AS __attribute__((address_space(1)))
#define LDS_AS __attribute__((address_space(3)))

__device__ __forceinline__ unsigned short f2bf(float x) {
  unsigned int u = __builtin_bit_cast(unsigned int, x);
  u += 0x7FFFu + ((u >> 16) & 1u);  // round-to-nearest-even
  return (unsigned short)(u >> 16);
}

__global__ void k_zero(float* __restrict__ row_pos, float* __restrict__ row_neg,
                       int* __restrict__ cnt) {
  int i = blockIdx.x * blockDim.x + threadIdx.x;
  if (i < NROW) { row_pos[i] = 0.0f; row_neg[i] = 0.0f; }
  if (i < NCLS) cnt[i] = 0;
}

// One wave per row: L2-norm, scale, cast to bf16; label histogram.
__global__ void __launch_bounds__(256) k_prep(
    const float* __restrict__ reps, const int* __restrict__ labels,
    unsigned short* __restrict__ Rb, int* __restrict__ cnt) {
  const int wave = threadIdx.x >> 6;
  const int lane = threadIdx.x & 63;
  const int row = blockIdx.x * 4 + wave;
  const float* r = reps + (size_t)row * DDIM;
  float4 v0 = *(const float4*)(r + lane * 4);
  float4 v1 = *(const float4*)(r + 256 + lane * 4);
  float ss = v0.x * v0.x + v0.y * v0.y + v0.z * v0.z + v0.w * v0.w +
             v1.x * v1.x + v1.y * v1.y + v1.z * v1.z + v1.w * v1.w;
#pragma unroll
  for (int m = 1; m < 64; m <<= 1) ss += __shfl_xor(ss, m);
  const float scale = 1.0f / sqrtf(ss);  // norms ~22.6; 1e-8 clamp unreachable
  ushort4 a, b;
  a.x = f2bf(v0.x * scale); a.y = f2bf(v0.y * scale);
  a.z = f2bf(v0.z * scale); a.w = f2bf(v0.w * scale);
  b.x = f2bf(v1.x * scale); b.y = f2bf(v1.y * scale);
  b.z = f2bf(v1.z * scale); b.w = f2bf(v1.w * scale);
  *(ushort4*)(Rb + (size_t)row * DDIM + lane * 4) = a;
  *(ushort4*)(Rb + (size_t)row * DDIM + 256 + lane * 4) = b;
  if (lane == 0) atomicAdd(&cnt[labels[row]], 1);
}

// 128x128 block tile, BK=32, 4 waves in 2x2, each wave 4x4 of 16x16x32 MFMA.
// Upper triangle only (bj >= bi); off-diagonal blocks also scatter col-sums.
__global__ void __launch_bounds__(256) k_gemm(
    const unsigned short* __restrict__ Rb, const int* __restrict__ labels,
    float* __restrict__ row_pos, float* __restrict__ row_neg) {
  const int bi = blockIdx.y, bj = blockIdx.x;
  if (bj < bi) return;

  __shared__ __attribute__((aligned(16))) unsigned short As[128 * 32];
  __shared__ __attribute__((aligned(16))) unsigned short Bs[128 * 32];
  __shared__ int labI[128];
  __shared__ int labJ[128];

  const int tid = threadIdx.x;
  const int lane = tid & 63;
  const int wave = tid >> 6;
  const int wr = wave >> 1, wc = wave & 1;
  const int quad = lane >> 4, c16 = lane & 15;
  const int i0 = bi * 128, j0 = bj * 128;

  if (tid < 128) labI[tid] = labels[i0 + tid];
  else labJ[tid - 128] = labels[j0 + tid - 128];

  f32x4 acc[4][4];
#pragma unroll
  for (int a = 0; a < 4; ++a)
#pragma unroll
    for (int b = 0; b < 4; ++b) acc[a][b] = (f32x4)0.0f;

  for (int it = 0; it < 16; ++it) {
    const int k0 = it * 32;
    __syncthreads();
#pragma unroll
    for (int t = 0; t < 2; ++t) {
      const int cb = wave * 64 + t * 256;   // wave-uniform chunk base
      const int c = cb + lane;              // this lane's 16B chunk
      const int rrow = c >> 2;
      const int kc = c & 3;
      const unsigned short* srcA = Rb + (size_t)(i0 + rrow) * DDIM + k0 + kc * 8;
      const unsigned short* srcB = Rb + (size_t)(j0 + rrow) * DDIM + k0 + kc * 8;
      __builtin_amdgcn_global_load_lds(
          (GLOBAL_AS void*)const_cast<unsigned short*>(srcA),
          (LDS_AS void*)(As + cb * 8), 16, 0, 0);
      __builtin_amdgcn_global_load_lds(
          (GLOBAL_AS void*)const_cast<unsigned short*>(srcB),
          (LDS_AS void*)(Bs + cb * 8), 16, 0, 0);
    }
    __syncthreads();

    s16x8 af[4], bfr[4];
#pragma unroll
    for (int a = 0; a < 4; ++a)
      af[a] = *(const s16x8*)(As + (wr * 64 + a * 16 + c16) * 32 + quad * 8);
#pragma unroll
    for (int b = 0; b < 4; ++b)
      bfr[b] = *(const s16x8*)(Bs + (wc * 64 + b * 16 + c16) * 32 + quad * 8);
#pragma unroll
    for (int a = 0; a < 4; ++a)
#pragma unroll
      for (int b = 0; b < 4; ++b)
        acc[a][b] = __builtin_amdgcn_mfma_f32_16x16x32_bf16(af[a], bfr[b],
                                                            acc[a][b], 0, 0, 0);
  }

  // score(shifted by S=10) = ((1+g)/2 + 1e-8)/0.1 - 10 = 5g - 5 + 1e-7
  const float C0 = -5.0f + 1e-7f;

  // Row-side accumulation (every block).
#pragma unroll
  for (int a = 0; a < 4; ++a) {
#pragma unroll
    for (int r = 0; r < 4; ++r) {
      const int ri = wr * 64 + a * 16 + quad * 4 + r;
      const int gi = i0 + ri;
      const int li = labI[ri];
      float ps = 0.0f, ns = 0.0f;
#pragma unroll
      for (int b = 0; b < 4; ++b) {
        const int cj = wc * 64 + b * 16 + c16;
        const int gj = j0 + cj;
        const int lj = labJ[cj];
        const float s = fmaf(acc[a][b][r], 5.0f, C0);
        if (li == lj) {
          if (gi != gj) ps += s;       // positive, off-diagonal
        } else {
          ns += __expf(s);             // negative (diag is same-label)
        }
      }
#pragma unroll
      for (int m = 1; m < 16; m <<= 1) {
        ps += __shfl_xor(ps, m);
        ns += __shfl_xor(ns, m);
      }
      if (c16 == 0) {
        atomicAdd(&row_pos[gi], ps);
        atomicAdd(&row_neg[gi], ns);
      }
    }
  }

  // Col-side accumulation (symmetric contribution, off-diagonal blocks only).
  if (bi != bj) {
#pragma unroll
    for (int b = 0; b < 4; ++b) {
      const int cj = wc * 64 + b * 16 + c16;
      const int gj = j0 + cj;
      const int lj = labJ[cj];
      float ps = 0.0f, ns = 0.0f;
#pragma unroll
      for (int a = 0; a < 4; ++a) {
#pragma unroll
        for (int r = 0; r < 4; ++r) {
          const int li = labI[wr * 64 + a * 16 + quad * 4 + r];
          const float s = fmaf(acc[a][b][r], 5.0f, C0);
          if (li == lj) ps += s;       // gi != gj guaranteed (bi != bj)
          else ns += __expf(s);
        }
      }
      ps += __shfl_xor(ps, 16); ns += __shfl_xor(ns, 16);
      ps += __shfl_xor(ps, 32); ns += __shfl_xor(ns, 32);
      if (quad == 0) {
        atomicAdd(&row_pos[gj], ps);
        atomicAdd(&row_neg[gj], ns);
      }
    }
  }
}

__global__ void __launch_bounds__(512) k_final(
    const float* __restrict__ row_pos, const float* __restrict__ row_neg,
    const int* __restrict__ labels, const int* __restrict__ cnt,
    float* __restrict__ out) {
  __shared__ float ssum[8];
  __shared__ float scnt[8];
  const int tid = threadIdx.x;
  float lsum = 0.0f, lcnt = 0.0f;
  for (int i = tid; i < NROW; i += 512) {
    const float c = (float)(cnt[labels[i]] - 1);
    const float pos = row_pos[i] / (c + 1e-8f);
    const float loss = -pos + logf(row_neg[i] + 1e-8f);
    if (loss > 0.0f) { lsum += loss; lcnt += 1.0f; }
  }
#pragma unroll
  for (int m = 1; m < 64; m <<= 1) {
    lsum += __shfl_xor(lsum, m);
    lcnt += __shfl_xor(lcnt, m);
  }
  if ((tid & 63) == 0) { ssum[tid >> 6] = lsum; scnt[tid >> 6] = lcnt; }
  __syncthreads();
  if (tid == 0) {
    float S = 0.0f, C = 0.0f;
#pragma unroll
    for (int w = 0; w < 8; ++w) { S += ssum[w]; C += scnt[w]; }
    out[0] = S / (C + 1e-8f);
  }
}

extern "C" void kernel_launch(void* const* d_in, const int* in_sizes, int n_in,
                              void* d_out, int out_size, void* d_ws, size_t ws_size,
                              hipStream_t stream) {
  const float* reps = (const float*)d_in[0];
  const int* labels = (const int*)d_in[1];
  float* out = (float*)d_out;
  char* ws = (char*)d_ws;
  // ws layout: Rb (bf16 normalized reps, 8 MiB) | row_pos | row_neg | cnt
  unsigned short* Rb = (unsigned short*)ws;
  float* row_pos = (float*)(ws + (size_t)NROW * DDIM * 2);
  float* row_neg = row_pos + NROW;
  int* cnt = (int*)(row_neg + NROW);

  k_zero<<<32, 256, 0, stream>>>(row_pos, row_neg, cnt);
  k_prep<<<NROW / 4, 256, 0, stream>>>(reps, labels, Rb, cnt);
  dim3 grid(64, 64);
  k_gemm<<<grid, 256, 0, stream>>>(Rb, labels, row_pos, row_neg);
  k_final<<<1, 512, 0, stream>>>(row_pos, row_neg, labels, cnt, out);
  (void)in_sizes; (void)n_in; (void)out_size; (void)ws_size;
}